// Round 6
// baseline (479.681 us; speedup 1.0000x reference)
//
#include <hip/hip_runtime.h>

#define B 128
#define HC 2
#define H1 2048
#define FS2 4096
#define NK 2048
#define OC 4
#define SPL2 512
#define NOUT 10
#define T 64
#define HBH (HC*B*H1)

typedef __attribute__((ext_vector_type(8))) short bf16x8;
typedef __attribute__((ext_vector_type(4))) float f32x4;

__device__ __forceinline__ unsigned short f2bf(float f) {
  unsigned u = __float_as_uint(f);
  u += 0x7fff + ((u >> 16) & 1);   // RNE
  return (unsigned short)(u >> 16);
}
__device__ __forceinline__ float bf2f(unsigned short s) {
  return __uint_as_float(((unsigned)s) << 16);
}

__device__ __forceinline__ void gload16(const void* g, void* l) {
  __builtin_amdgcn_global_load_lds(
      (const __attribute__((address_space(1))) unsigned int*)g,
      (__attribute__((address_space(3))) unsigned int*)l, 16, 0, 0);
}

__global__ __launch_bounds__(256) void init_state(float* __restrict__ p, int n) {
  int i = blockIdx.x * 256 + threadIdx.x;
  if (i < n) p[i] = 0.f;
}

// x fp32 -> hi/lo bf16
__global__ __launch_bounds__(256) void conv_x(
    const float4* __restrict__ xin, ushort4* __restrict__ xh,
    ushort4* __restrict__ xl, int n4) {
  for (int i = blockIdx.x * 256 + threadIdx.x; i < n4; i += gridDim.x * 256) {
    float4 v = xin[i];
    ushort4 h, lo;
    h.x = f2bf(v.x); h.y = f2bf(v.y); h.z = f2bf(v.z); h.w = f2bf(v.w);
    lo.x = f2bf(v.x - bf2f(h.x)); lo.y = f2bf(v.y - bf2f(h.y));
    lo.z = f2bf(v.z - bf2f(h.z)); lo.w = f2bf(v.w - bf2f(h.w));
    xh[i] = h; xl[i] = lo;
  }
}

// w_hidden [HC][K][N] fp32 -> wt hi/lo [HC][N][K] bf16 (transpose)
__global__ __launch_bounds__(256) void conv_w(
    const float* __restrict__ w, unsigned short* __restrict__ wth,
    unsigned short* __restrict__ wtl) {
  __shared__ float s[64][65];
  const int c = blockIdx.z;
  const int n0 = blockIdx.x * 64, k0 = blockIdx.y * 64;
  const int tid = threadIdx.x;
  const int r = tid >> 4, c4 = (tid & 15) * 4;
#pragma unroll
  for (int q = 0; q < 4; ++q) {
    int kr = r + q * 16;
    float4 v = *(const float4*)(w + ((size_t)c * NK + k0 + kr) * H1 + n0 + c4);
    s[kr][c4 + 0] = v.x; s[kr][c4 + 1] = v.y;
    s[kr][c4 + 2] = v.z; s[kr][c4 + 3] = v.w;
  }
  __syncthreads();
#pragma unroll
  for (int q = 0; q < 4; ++q) {
    int nr = r + q * 16;
    float a0 = s[c4 + 0][nr], a1 = s[c4 + 1][nr];
    float a2 = s[c4 + 2][nr], a3 = s[c4 + 3][nr];
    ushort4 h, lo;
    h.x = f2bf(a0); h.y = f2bf(a1); h.z = f2bf(a2); h.w = f2bf(a3);
    lo.x = f2bf(a0 - bf2f(h.x)); lo.y = f2bf(a1 - bf2f(h.y));
    lo.z = f2bf(a2 - bf2f(h.z)); lo.w = f2bf(a3 - bf2f(h.w));
    size_t off = ((size_t)c * H1 + n0 + nr) * NK + k0 + c4;
    *(ushort4*)(wth + off) = h;
    *(ushort4*)(wtl + off) = lo;
  }
}

// BM=256 x BN=128, BK=32, 3-buffer pipelined split GEMM (counted vmcnt,
// R3 schedule) + 2D XCD-blocked placement (R4): c = xcd&1, quadrant
// q = xcd>>1 owns mb in [q*nMblk/4, ...), nb (16) inner.
// LDS buffer (48KB): Ah@0, Al@8192, Bh@16384, Bl@20480 (shorts); 3 bufs.
// 8 waves as 4(m) x 2(n); wave tile 64x64; 48 MFMA/tile in 2 phases.
__global__ __launch_bounds__(512, 2) void gemm_split(
    const unsigned short* __restrict__ xh, const unsigned short* __restrict__ xl,
    const unsigned short* __restrict__ wth, const unsigned short* __restrict__ wtl,
    float* __restrict__ cur, int Mc, int nMblk) {
  const int bid = blockIdx.x;
  int c, nb, mb;
  if ((nMblk & 3) == 0) {
    const int xcd = bid & 7;
    const int slot = bid >> 3;          // 0 .. 4*nMblk-1
    c = xcd & 1;
    const int q = xcd >> 1;             // 0..3
    const int mq = nMblk >> 2;
    nb = slot & 15;
    mb = q * mq + (slot >> 4);
  } else {
    mb = bid % nMblk;
    int rest = bid / nMblk;
    nb = rest & 15;
    c = rest >> 4;
  }
  const int bm = mb * 256, bn = nb * 128;

  __shared__ unsigned short lds[73728];
  const int tid = threadIdx.x;

  // staging maps (linear LDS dest; source slot-rotated for conflict-free reads)
  size_t srcA[2]; unsigned dstA[2];
#pragma unroll
  for (int q = 0; q < 2; ++q) {
    int idx = q * 512 + tid;
    int row = idx >> 2, ps = idx & 3;
    int ks = (ps - (row >> 1)) & 3;
    int ar = bm + row; if (ar > Mc - 1) ar = Mc - 1;
    srcA[q] = (size_t)ar * FS2 + (size_t)c * NK + ks * 8;
    dstA[q] = idx * 8;
  }
  size_t srcB; unsigned dstB;
  {
    int row = tid >> 2, ps = tid & 3;
    int ks = (ps - (row >> 1)) & 3;
    srcB = (size_t)c * NK * H1 + (size_t)(bn + row) * NK + ks * 8;
    dstB = tid * 8;
  }

  const int l = tid & 63, w = tid >> 6;
  const int wr = w >> 1, wc = w & 1;
  const int lrow = l & 15, lks = l >> 4;
  unsigned aoff[4], boff[4];
#pragma unroll
  for (int m = 0; m < 4; ++m) {
    int row = wr * 64 + m * 16 + lrow;
    int ps = (lks + (row >> 1)) & 3;
    aoff[m] = row * 32 + ps * 8;
  }
#pragma unroll
  for (int n = 0; n < 4; ++n) {
    int rn = wc * 64 + n * 16 + lrow;
    int ps = (lks + (rn >> 1)) & 3;
    boff[n] = rn * 32 + ps * 8;
  }

  f32x4 acc[4][4];
#pragma unroll
  for (int m = 0; m < 4; ++m)
#pragma unroll
    for (int n = 0; n < 4; ++n) acc[m][n] = (f32x4){0.f, 0.f, 0.f, 0.f};

#define STAGE_A(bufbase, k0)                                      \
  do {                                                            \
    gload16(xh + srcA[0] + (k0), &lds[(bufbase) + dstA[0]]);      \
    gload16(xh + srcA[1] + (k0), &lds[(bufbase) + dstA[1]]);      \
    gload16(wth + srcB + (k0), &lds[(bufbase) + 16384 + dstB]);   \
  } while (0)
#define STAGE_B(bufbase, k0)                                          \
  do {                                                                \
    gload16(xl + srcA[0] + (k0), &lds[(bufbase) + 8192 + dstA[0]]);   \
    gload16(xl + srcA[1] + (k0), &lds[(bufbase) + 8192 + dstA[1]]);   \
    gload16(wtl + srcB + (k0), &lds[(bufbase) + 20480 + dstB]);       \
  } while (0)

  const int NT = NK / 32;
  // prologue: stage tiles 0,1 (12 gloads); wait first 6 (tile 0) landed
  STAGE_A(0, 0);  STAGE_B(0, 0);
  STAGE_A(24576, 32);  STAGE_B(24576, 32);
  asm volatile("s_waitcnt vmcnt(6)" ::: "memory");
  __builtin_amdgcn_s_barrier();

  int cb = 0, pb = 2;   // compute buf, prefetch buf (t+2)
  for (int t = 0; t < NT; ++t) {
    const unsigned short* bc = &lds[cb * 24576];
    const unsigned pbase = pb * 24576;
    const int pf = (t + 2 < NT);
    const int kpre = (t + 2) * 32;

    // ---- phase 0: prefetch part A, read B frags + A m0/m1, 24 MFMA ----
    if (pf) STAGE_A(pbase, kpre);
    bf16x8 bh[4], bl[4], ah0, al0, ah1, al1;
#pragma unroll
    for (int n = 0; n < 4; ++n) {
      bh[n] = *(const bf16x8*)&bc[16384 + boff[n]];
      bl[n] = *(const bf16x8*)&bc[20480 + boff[n]];
    }
    ah0 = *(const bf16x8*)&bc[aoff[0]];
    al0 = *(const bf16x8*)&bc[8192 + aoff[0]];
    ah1 = *(const bf16x8*)&bc[aoff[1]];
    al1 = *(const bf16x8*)&bc[8192 + aoff[1]];
    asm volatile("s_waitcnt lgkmcnt(0)" ::: "memory");
    __builtin_amdgcn_sched_barrier(0);
    __builtin_amdgcn_s_setprio(1);
#pragma unroll
    for (int n = 0; n < 4; ++n) {
      acc[0][n] = __builtin_amdgcn_mfma_f32_16x16x32_bf16(ah0, bh[n], acc[0][n], 0, 0, 0);
      acc[0][n] = __builtin_amdgcn_mfma_f32_16x16x32_bf16(ah0, bl[n], acc[0][n], 0, 0, 0);
      acc[0][n] = __builtin_amdgcn_mfma_f32_16x16x32_bf16(al0, bh[n], acc[0][n], 0, 0, 0);
      acc[1][n] = __builtin_amdgcn_mfma_f32_16x16x32_bf16(ah1, bh[n], acc[1][n], 0, 0, 0);
      acc[1][n] = __builtin_amdgcn_mfma_f32_16x16x32_bf16(ah1, bl[n], acc[1][n], 0, 0, 0);
      acc[1][n] = __builtin_amdgcn_mfma_f32_16x16x32_bf16(al1, bh[n], acc[1][n], 0, 0, 0);
    }
    __builtin_amdgcn_s_setprio(0);

    // ---- phase 1: prefetch part B, read A m2/m3, 24 MFMA ----
    if (pf) STAGE_B(pbase, kpre);
    bf16x8 ah2, al2, ah3, al3;
    ah2 = *(const bf16x8*)&bc[aoff[2]];
    al2 = *(const bf16x8*)&bc[8192 + aoff[2]];
    ah3 = *(const bf16x8*)&bc[aoff[3]];
    al3 = *(const bf16x8*)&bc[8192 + aoff[3]];
    asm volatile("s_waitcnt lgkmcnt(0)" ::: "memory");
    __builtin_amdgcn_sched_barrier(0);
    __builtin_amdgcn_s_setprio(1);
#pragma unroll
    for (int n = 0; n < 4; ++n) {
      acc[2][n] = __builtin_amdgcn_mfma_f32_16x16x32_bf16(ah2, bh[n], acc[2][n], 0, 0, 0);
      acc[2][n] = __builtin_amdgcn_mfma_f32_16x16x32_bf16(ah2, bl[n], acc[2][n], 0, 0, 0);
      acc[2][n] = __builtin_amdgcn_mfma_f32_16x16x32_bf16(al2, bh[n], acc[2][n], 0, 0, 0);
      acc[3][n] = __builtin_amdgcn_mfma_f32_16x16x32_bf16(ah3, bh[n], acc[3][n], 0, 0, 0);
      acc[3][n] = __builtin_amdgcn_mfma_f32_16x16x32_bf16(ah3, bl[n], acc[3][n], 0, 0, 0);
      acc[3][n] = __builtin_amdgcn_mfma_f32_16x16x32_bf16(al3, bh[n], acc[3][n], 0, 0, 0);
    }
    __builtin_amdgcn_s_setprio(0);

    // ---- end of tile: counted wait (tile t+1 landed), raw barrier ----
    if (t + 1 < NT) {
      if (pf) asm volatile("s_waitcnt vmcnt(6)" ::: "memory");
      else    asm volatile("s_waitcnt vmcnt(0)" ::: "memory");
      __builtin_amdgcn_s_barrier();
    }
    cb = (cb == 2) ? 0 : cb + 1;
    pb = (pb == 2) ? 0 : pb + 1;
  }
#undef STAGE_A
#undef STAGE_B

  float* Cc = cur + (size_t)c * Mc * H1;
#pragma unroll
  for (int m = 0; m < 4; ++m) {
    int grow = bm + wr * 64 + m * 16 + (l >> 4) * 4;
    if (grow < Mc) {
#pragma unroll
      for (int n = 0; n < 4; ++n) {
        int gcol = bn + wc * 64 + n * 16 + (l & 15);
        float* Cp = Cc + (size_t)grow * H1 + gcol;
        Cp[0]      = acc[m][n][0];
        Cp[H1]     = acc[m][n][1];
        Cp[2 * H1] = acc[m][n][2];
        Cp[3 * H1] = acc[m][n][3];
      }
    }
  }
}

// sequential dynamics: one block per (b, oc); defers readout via sp_g spikes
__global__ __launch_bounds__(256) void seq_chunk(
    const float* __restrict__ cur, const float* __restrict__ wout,
    float* __restrict__ vdh, float* __restrict__ idh,
    float* __restrict__ vsh, float* __restrict__ ish,
    float* __restrict__ vdo, float* __restrict__ ido,
    float* __restrict__ sp_g, int t0, int tc, int Mc) {
  const int b = blockIdx.x >> 2;
  const int oc = blockIdx.x & 3;
  const int tid = threadIdx.x;
  __shared__ float wols[SPL2 * NOUT];  // 20KB
  __shared__ float zls[SPL2];
  __shared__ float cols[16];

#pragma unroll
  for (int q = 0; q < 5; ++q) {
    int i4 = q * 256 + tid;
    ((float4*)wols)[i4] = ((const float4*)(wout + (size_t)oc * SPL2 * NOUT))[i4];
  }
  const int hb = oc * SPL2;
  float vdl[HC][2], idl[HC][2], vsl[2], isl[2];
#pragma unroll
  for (int c = 0; c < HC; ++c)
#pragma unroll
    for (int u = 0; u < 2; ++u) {
      size_t o = ((size_t)c * B + b) * H1 + hb + tid + u * 256;
      vdl[c][u] = vdh[o]; idl[c][u] = idh[o];
    }
#pragma unroll
  for (int u = 0; u < 2; ++u) {
    size_t o = (size_t)b * H1 + hb + tid + u * 256;
    vsl[u] = vsh[o]; isl[u] = ish[o];
  }
  float vo = 0.f, io = 0.f;
  if (tid < NOUT) {
    vo = vdo[(oc * B + b) * NOUT + tid];
    io = ido[(oc * B + b) * NOUT + tid];
  }
  float pc[HC][2];
#pragma unroll
  for (int c = 0; c < HC; ++c)
#pragma unroll
    for (int u = 0; u < 2; ++u)
      pc[c][u] = cur[((size_t)c * Mc + b) * H1 + hb + tid + u * 256];

  for (int tl = 0; tl < tc; ++tl) {
#pragma unroll
    for (int u = 0; u < 2; ++u) {
      float zsum = 0.f;
#pragma unroll
      for (int c = 0; c < HC; ++c) {
        float v = vdl[c][u], i = idl[c][u];
        float vdec = v + 0.1f * (i - v);
        float idec = 0.8f * i;
        bool z = (vdec - 1.0f) > 0.f;
        vdl[c][u] = z ? 0.f : vdec;
        idl[c][u] = idec + pc[c][u];
        zsum += z ? 1.f : 0.f;
      }
      float v = vsl[u], i = isl[u];
      float vdec = v + 0.1f * (i - v);
      float idec = 0.8f * i;
      bool z = (vdec - 1.0f) > 0.f;
      vsl[u] = z ? 0.f : vdec;
      isl[u] = idec + zsum;
      zls[tid + u * 256] = z ? 1.f : 0.f;
    }
    if (tl + 1 < tc) {
#pragma unroll
      for (int c = 0; c < HC; ++c)
#pragma unroll
        for (int u = 0; u < 2; ++u)
          pc[c][u] = cur[((size_t)c * Mc + (tl + 1) * B + b) * H1 + hb + tid + u * 256];
    }
    __syncthreads();
    {
      const int g = tid >> 4, li = tid & 15;
      if (g < NOUT) {
        float s = 0.f;
#pragma unroll
        for (int j = 0; j < 32; ++j) {
          int i2 = li + 16 * j;
          s += zls[i2] * wols[i2 * NOUT + g];
        }
        s += __shfl_xor(s, 1); s += __shfl_xor(s, 2);
        s += __shfl_xor(s, 4); s += __shfl_xor(s, 8);
        if (li == 0) cols[g] = s;
      }
    }
    __syncthreads();
    if (tid < NOUT) {
      float vdec = vo + 0.1f * (io - vo);
      float idec = 0.8f * io;
      bool z = (vdec - 1.0f) > 0.f;
      vo = z ? 0.f : vdec;
      io = idec + cols[tid];
      sp_g[((size_t)(t0 + tl) * B + b) * (OC * NOUT) + oc * NOUT + tid] = z ? 1.f : 0.f;
    }
  }

#pragma unroll
  for (int c = 0; c < HC; ++c)
#pragma unroll
    for (int u = 0; u < 2; ++u) {
      size_t o = ((size_t)c * B + b) * H1 + hb + tid + u * 256;
      vdh[o] = vdl[c][u]; idh[o] = idl[c][u];
    }
#pragma unroll
  for (int u = 0; u < 2; ++u) {
    size_t o = (size_t)b * H1 + hb + tid + u * 256;
    vsh[o] = vsl[u]; ish[o] = isl[u];
  }
  if (tid < NOUT) {
    vdo[(oc * B + b) * NOUT + tid] = vo;
    ido[(oc * B + b) * NOUT + tid] = io;
  }
}

// final readout integration over stored output spikes
__global__ __launch_bounds__(256) void integrate_out(
    const float* __restrict__ sp_g, float* __restrict__ out) {
  int i = blockIdx.x * 256 + threadIdx.x;
  if (i >= B * NOUT) return;
  int b = i / NOUT, o = i % NOUT;
  float vr = 0.f, ir = 0.f;
  for (int t = 0; t < T; ++t) {
    const float* p = sp_g + ((size_t)(t * B + b) * OC) * NOUT + o;
    float ssum = ((p[0] + p[NOUT]) + p[2 * NOUT]) + p[3 * NOUT];
    float vn = vr + 0.1f * (ir - vr);
    ir = 0.8f * ir + ssum;
    vr = vn;
    out[(size_t)(t * B + b) * NOUT + o] = vn;
  }
}

extern "C" void kernel_launch(void* const* d_in, const int* in_sizes, int n_in,
                              void* d_out, int out_size, void* d_ws, size_t ws_size,
                              hipStream_t stream) {
  const float* x  = (const float*)d_in[0];
  const float* wh = (const float*)d_in[1];
  const float* wo = (const float*)d_in[2];
  float* out = (float*)d_out;
  char* ws = (char*)d_ws;

  unsigned short* wth = (unsigned short*)ws;
  unsigned short* wtl = wth + (size_t)HC * NK * H1;
  float* st  = (float*)(wtl + (size_t)HC * NK * H1);
  float* vdh = st;
  float* idh = vdh + HBH;
  float* vsh = idh + HBH;
  float* ish = vsh + (size_t)B * H1;
  float* vdo = ish + (size_t)B * H1;
  float* ido = vdo + OC * B * NOUT;
  float* sp_g = ido + OC * B * NOUT;
  float* dyn = sp_g + (size_t)T * B * OC * NOUT;
  const int NSTATE = (int)(sp_g - st);

  size_t fixed_bytes = (size_t)((char*)dyn - ws);
  size_t avail = (ws_size > fixed_bytes + 256) ? ws_size - fixed_bytes - 256 : 0;
  const size_t per_t = (size_t)HC * B * H1 * 4 + (size_t)B * FS2 * 2 * 2;  // 4MB
  int Tc = (int)(avail / per_t);
  if (Tc > T) Tc = T;
  if (Tc >= 2) Tc &= ~1;
  if (Tc < 1) Tc = 1;

  float* cur = dyn;
  unsigned short* xh = (unsigned short*)(cur + (size_t)Tc * HC * B * H1);
  unsigned short* xl = xh + (size_t)Tc * B * FS2;

  init_state<<<(NSTATE + 255) / 256, 256, 0, stream>>>(st, NSTATE);
  conv_w<<<dim3(H1 / 64, NK / 64, HC), 256, 0, stream>>>(wh, wth, wtl);

  for (int t0 = 0; t0 < T; t0 += Tc) {
    int tc = (T - t0 < Tc) ? (T - t0) : Tc;
    int Mc = tc * B;
    int n4 = Mc * (FS2 / 4);
    int cb = (n4 + 255) / 256; if (cb > 2048) cb = 2048;
    conv_x<<<cb, 256, 0, stream>>>((const float4*)(x + (size_t)t0 * B * FS2),
                                   (ushort4*)xh, (ushort4*)xl, n4);
    int nMblk = (Mc + 255) / 256;
    gemm_split<<<HC * 16 * nMblk, 512, 0, stream>>>(xh, xl, wth, wtl, cur, Mc, nMblk);
    seq_chunk<<<B * OC, 256, 0, stream>>>(cur, wo, vdh, idh, vsh, ish,
                                          vdo, ido, sp_g, t0, tc, Mc);
  }
  integrate_out<<<(B * NOUT + 255) / 256, 256, 0, stream>>>(sp_g, out);
}

// Round 7
// 427.256 us; speedup vs baseline: 1.1227x; 1.1227x over previous
//
#include <hip/hip_runtime.h>

#define B 128
#define HC 2
#define H1 2048
#define FS2 4096
#define NK 2048
#define OC 4
#define SPL2 512
#define NOUT 10
#define T 64
#define HBH (HC*B*H1)

typedef __attribute__((ext_vector_type(8))) short bf16x8;
typedef __attribute__((ext_vector_type(4))) float f32x4;

__device__ __forceinline__ unsigned short f2bf(float f) {
  unsigned u = __float_as_uint(f);
  u += 0x7fff + ((u >> 16) & 1);   // RNE
  return (unsigned short)(u >> 16);
}
__device__ __forceinline__ float bf2f(unsigned short s) {
  return __uint_as_float(((unsigned)s) << 16);
}

__device__ __forceinline__ void gload16(const void* g, void* l) {
  __builtin_amdgcn_global_load_lds(
      (const __attribute__((address_space(1))) unsigned int*)g,
      (__attribute__((address_space(3))) unsigned int*)l, 16, 0, 0);
}

__global__ __launch_bounds__(256) void init_state(float* __restrict__ p, int n) {
  int i = blockIdx.x * 256 + threadIdx.x;
  if (i < n) p[i] = 0.f;
}

// x fp32 -> hi/lo bf16
__global__ __launch_bounds__(256) void conv_x(
    const float4* __restrict__ xin, ushort4* __restrict__ xh,
    ushort4* __restrict__ xl, int n4) {
  for (int i = blockIdx.x * 256 + threadIdx.x; i < n4; i += gridDim.x * 256) {
    float4 v = xin[i];
    ushort4 h, lo;
    h.x = f2bf(v.x); h.y = f2bf(v.y); h.z = f2bf(v.z); h.w = f2bf(v.w);
    lo.x = f2bf(v.x - bf2f(h.x)); lo.y = f2bf(v.y - bf2f(h.y));
    lo.z = f2bf(v.z - bf2f(h.z)); lo.w = f2bf(v.w - bf2f(h.w));
    xh[i] = h; xl[i] = lo;
  }
}

// w_hidden [HC][K][N] fp32 -> wt hi/lo [HC][N][K] bf16 (transpose)
__global__ __launch_bounds__(256) void conv_w(
    const float* __restrict__ w, unsigned short* __restrict__ wth,
    unsigned short* __restrict__ wtl) {
  __shared__ float s[64][65];
  const int c = blockIdx.z;
  const int n0 = blockIdx.x * 64, k0 = blockIdx.y * 64;
  const int tid = threadIdx.x;
  const int r = tid >> 4, c4 = (tid & 15) * 4;
#pragma unroll
  for (int q = 0; q < 4; ++q) {
    int kr = r + q * 16;
    float4 v = *(const float4*)(w + ((size_t)c * NK + k0 + kr) * H1 + n0 + c4);
    s[kr][c4 + 0] = v.x; s[kr][c4 + 1] = v.y;
    s[kr][c4 + 2] = v.z; s[kr][c4 + 3] = v.w;
  }
  __syncthreads();
#pragma unroll
  for (int q = 0; q < 4; ++q) {
    int nr = r + q * 16;
    float a0 = s[c4 + 0][nr], a1 = s[c4 + 1][nr];
    float a2 = s[c4 + 2][nr], a3 = s[c4 + 3][nr];
    ushort4 h, lo;
    h.x = f2bf(a0); h.y = f2bf(a1); h.z = f2bf(a2); h.w = f2bf(a3);
    lo.x = f2bf(a0 - bf2f(h.x)); lo.y = f2bf(a1 - bf2f(h.y));
    lo.z = f2bf(a2 - bf2f(h.z)); lo.w = f2bf(a3 - bf2f(h.w));
    size_t off = ((size_t)c * H1 + n0 + nr) * NK + k0 + c4;
    *(ushort4*)(wth + off) = h;
    *(ushort4*)(wtl + off) = lo;
  }
}

// 256x256, BK=32, double-buffered split GEMM with 3 term-phases per K-tile
// (hh / hl / lh) and counted-vmcnt group staging:
//   G1={Ah,Bh} (4 loads) @P1, G2={Bl} (2) @P2, G3={Al} (2) @P3, each into
//   buf[next]; phase-entry waits vmcnt(4)/(6)/(6) — never a full drain.
// Per-acc term order stays hh->hl->lh (bitwise identical to R4).
// Placement (R4, proven): c = xcd&1, quadrant xcd>>1 owns mb range, 8 nb inner.
__global__ __launch_bounds__(512, 2) void gemm_split(
    const unsigned short* __restrict__ xh, const unsigned short* __restrict__ xl,
    const unsigned short* __restrict__ wth, const unsigned short* __restrict__ wtl,
    float* __restrict__ cur, int Mc, int nMblk) {
  const int bid = blockIdx.x;
  int c, nb, mb;
  if ((nMblk & 3) == 0) {
    const int xcd = bid & 7;
    const int slot = bid >> 3;
    c = xcd & 1;
    const int q = xcd >> 1;
    const int mq = nMblk >> 2;
    nb = slot & 7;
    mb = q * mq + (slot >> 3);
  } else {
    mb = bid % nMblk;
    int rest = bid / nMblk;
    nb = rest & 7;
    c = rest >> 3;
  }
  const int bm = mb * 256, bn = nb * 256;

  __shared__ unsigned short lds[65536];  // 2 bufs x {Ah,Al,Bh,Bl} x 8192
  const int tid = threadIdx.x;

  // staging maps (linear LDS dest = lane x 16B; source slot-rotated)
  unsigned dstOff[2]; size_t srcA[2], srcB[2];
#pragma unroll
  for (int q = 0; q < 2; ++q) {
    int idx = q * 512 + tid;
    int row = idx >> 2, ps = idx & 3;
    int ks = (ps - (row >> 1)) & 3;
    int ar = bm + row; if (ar > Mc - 1) ar = Mc - 1;
    srcA[q] = (size_t)ar * FS2 + (size_t)c * NK + ks * 8;
    srcB[q] = (size_t)c * NK * H1 + (size_t)(bn + row) * NK + ks * 8;
    dstOff[q] = idx * 8;
  }

  const int l = tid & 63, w = tid >> 6;
  const int wr = w >> 2, wc = w & 3;          // 2 x 4 waves, wave tile 128x64
  const int lrow = l & 15, lks = l >> 4;
  unsigned aoff[8], boff[4];
#pragma unroll
  for (int m = 0; m < 8; ++m) {
    int row = wr * 128 + m * 16 + lrow;
    int ps = (lks + (row >> 1)) & 3;
    aoff[m] = row * 32 + ps * 8;
  }
#pragma unroll
  for (int n = 0; n < 4; ++n) {
    int rn = wc * 64 + n * 16 + lrow;
    int ps = (lks + (rn >> 1)) & 3;
    boff[n] = rn * 32 + ps * 8;
  }

  f32x4 acc[8][4];
#pragma unroll
  for (int m = 0; m < 8; ++m)
#pragma unroll
    for (int n = 0; n < 4; ++n) acc[m][n] = (f32x4){0.f, 0.f, 0.f, 0.f};

  // prologue: tile 0 groups in FIFO order G1, G2, G3 -> buf0
  gload16(xh  + srcA[0], &lds[dstOff[0]]);
  gload16(xh  + srcA[1], &lds[dstOff[1]]);
  gload16(wth + srcB[0], &lds[16384 + dstOff[0]]);
  gload16(wth + srcB[1], &lds[16384 + dstOff[1]]);
  gload16(wtl + srcB[0], &lds[24576 + dstOff[0]]);
  gload16(wtl + srcB[1], &lds[24576 + dstOff[1]]);
  gload16(xl  + srcA[0], &lds[8192 + dstOff[0]]);
  gload16(xl  + srcA[1], &lds[8192 + dstOff[1]]);

  const int NT = NK / 32;
  for (int t = 0; t < NT - 1; ++t) {
    const unsigned cb   = (unsigned)(t & 1) * 32768;
    const unsigned nbuf = (unsigned)((t + 1) & 1) * 32768;
    const int kn = (t + 1) * 32;

    // ---- P1: wait G1(t) (allow G2,G3(t) = 4), stage G1(t+1), hh MFMA ----
    asm volatile("s_waitcnt vmcnt(4)\ns_barrier" ::: "memory");
    gload16(xh  + srcA[0] + kn, &lds[nbuf + dstOff[0]]);
    gload16(xh  + srcA[1] + kn, &lds[nbuf + dstOff[1]]);
    gload16(wth + srcB[0] + kn, &lds[nbuf + 16384 + dstOff[0]]);
    gload16(wth + srcB[1] + kn, &lds[nbuf + 16384 + dstOff[1]]);
    bf16x8 bh[4], ah[8];
#pragma unroll
    for (int n = 0; n < 4; ++n) bh[n] = *(const bf16x8*)&lds[cb + 16384 + boff[n]];
#pragma unroll
    for (int m = 0; m < 8; ++m) ah[m] = *(const bf16x8*)&lds[cb + aoff[m]];
    __builtin_amdgcn_s_setprio(1);
#pragma unroll
    for (int m = 0; m < 8; ++m)
#pragma unroll
      for (int n = 0; n < 4; ++n)
        acc[m][n] = __builtin_amdgcn_mfma_f32_16x16x32_bf16(ah[m], bh[n], acc[m][n], 0, 0, 0);
    __builtin_amdgcn_s_setprio(0);

    // ---- P2: wait G2(t) (allow G3(t)+G1(t+1) = 6), stage G2(t+1), hl ----
    asm volatile("s_waitcnt vmcnt(6)\ns_barrier" ::: "memory");
    gload16(wtl + srcB[0] + kn, &lds[nbuf + 24576 + dstOff[0]]);
    gload16(wtl + srcB[1] + kn, &lds[nbuf + 24576 + dstOff[1]]);
    bf16x8 bl[4];
#pragma unroll
    for (int n = 0; n < 4; ++n) bl[n] = *(const bf16x8*)&lds[cb + 24576 + boff[n]];
    __builtin_amdgcn_s_setprio(1);
#pragma unroll
    for (int m = 0; m < 8; ++m)
#pragma unroll
      for (int n = 0; n < 4; ++n)
        acc[m][n] = __builtin_amdgcn_mfma_f32_16x16x32_bf16(ah[m], bl[n], acc[m][n], 0, 0, 0);
    __builtin_amdgcn_s_setprio(0);

    // ---- P3: wait G3(t) (allow G1,G2(t+1) = 6), stage G3(t+1), lh ----
    asm volatile("s_waitcnt vmcnt(6)\ns_barrier" ::: "memory");
    gload16(xl + srcA[0] + kn, &lds[nbuf + 8192 + dstOff[0]]);
    gload16(xl + srcA[1] + kn, &lds[nbuf + 8192 + dstOff[1]]);
    bf16x8 al[8];
#pragma unroll
    for (int m = 0; m < 8; ++m) al[m] = *(const bf16x8*)&lds[cb + 8192 + aoff[m]];
    __builtin_amdgcn_s_setprio(1);
#pragma unroll
    for (int m = 0; m < 8; ++m)
#pragma unroll
      for (int n = 0; n < 4; ++n)
        acc[m][n] = __builtin_amdgcn_mfma_f32_16x16x32_bf16(al[m], bh[n], acc[m][n], 0, 0, 0);
    __builtin_amdgcn_s_setprio(0);
  }

  // peeled last tile (no prefetch): waits are exact
  {
    const unsigned cb = (unsigned)((NT - 1) & 1) * 32768;
    asm volatile("s_waitcnt vmcnt(4)\ns_barrier" ::: "memory");
    bf16x8 bh[4], ah[8];
#pragma unroll
    for (int n = 0; n < 4; ++n) bh[n] = *(const bf16x8*)&lds[cb + 16384 + boff[n]];
#pragma unroll
    for (int m = 0; m < 8; ++m) ah[m] = *(const bf16x8*)&lds[cb + aoff[m]];
#pragma unroll
    for (int m = 0; m < 8; ++m)
#pragma unroll
      for (int n = 0; n < 4; ++n)
        acc[m][n] = __builtin_amdgcn_mfma_f32_16x16x32_bf16(ah[m], bh[n], acc[m][n], 0, 0, 0);
    asm volatile("s_waitcnt vmcnt(2)\ns_barrier" ::: "memory");
    bf16x8 bl[4];
#pragma unroll
    for (int n = 0; n < 4; ++n) bl[n] = *(const bf16x8*)&lds[cb + 24576 + boff[n]];
#pragma unroll
    for (int m = 0; m < 8; ++m)
#pragma unroll
      for (int n = 0; n < 4; ++n)
        acc[m][n] = __builtin_amdgcn_mfma_f32_16x16x32_bf16(ah[m], bl[n], acc[m][n], 0, 0, 0);
    asm volatile("s_waitcnt vmcnt(0)\ns_barrier" ::: "memory");
    bf16x8 al[8];
#pragma unroll
    for (int m = 0; m < 8; ++m) al[m] = *(const bf16x8*)&lds[cb + 8192 + aoff[m]];
#pragma unroll
    for (int m = 0; m < 8; ++m)
#pragma unroll
      for (int n = 0; n < 4; ++n)
        acc[m][n] = __builtin_amdgcn_mfma_f32_16x16x32_bf16(al[m], bh[n], acc[m][n], 0, 0, 0);
  }

  float* Cc = cur + (size_t)c * Mc * H1;
#pragma unroll
  for (int m = 0; m < 8; ++m) {
    int grow = bm + wr * 128 + m * 16 + (l >> 4) * 4;
    if (grow < Mc) {
#pragma unroll
      for (int n = 0; n < 4; ++n) {
        int gcol = bn + wc * 64 + n * 16 + (l & 15);
        float* Cp = Cc + (size_t)grow * H1 + gcol;
        Cp[0]      = acc[m][n][0];
        Cp[H1]     = acc[m][n][1];
        Cp[2 * H1] = acc[m][n][2];
        Cp[3 * H1] = acc[m][n][3];
      }
    }
  }
}

// sequential dynamics: one block per (b, oc); defers readout via sp_g spikes
__global__ __launch_bounds__(256) void seq_chunk(
    const float* __restrict__ cur, const float* __restrict__ wout,
    float* __restrict__ vdh, float* __restrict__ idh,
    float* __restrict__ vsh, float* __restrict__ ish,
    float* __restrict__ vdo, float* __restrict__ ido,
    float* __restrict__ sp_g, int t0, int tc, int Mc) {
  const int b = blockIdx.x >> 2;
  const int oc = blockIdx.x & 3;
  const int tid = threadIdx.x;
  __shared__ float wols[SPL2 * NOUT];  // 20KB
  __shared__ float zls[SPL2];
  __shared__ float cols[16];

#pragma unroll
  for (int q = 0; q < 5; ++q) {
    int i4 = q * 256 + tid;
    ((float4*)wols)[i4] = ((const float4*)(wout + (size_t)oc * SPL2 * NOUT))[i4];
  }
  const int hb = oc * SPL2;
  float vdl[HC][2], idl[HC][2], vsl[2], isl[2];
#pragma unroll
  for (int c = 0; c < HC; ++c)
#pragma unroll
    for (int u = 0; u < 2; ++u) {
      size_t o = ((size_t)c * B + b) * H1 + hb + tid + u * 256;
      vdl[c][u] = vdh[o]; idl[c][u] = idh[o];
    }
#pragma unroll
  for (int u = 0; u < 2; ++u) {
    size_t o = (size_t)b * H1 + hb + tid + u * 256;
    vsl[u] = vsh[o]; isl[u] = ish[o];
  }
  float vo = 0.f, io = 0.f;
  if (tid < NOUT) {
    vo = vdo[(oc * B + b) * NOUT + tid];
    io = ido[(oc * B + b) * NOUT + tid];
  }
  float pc[HC][2];
#pragma unroll
  for (int c = 0; c < HC; ++c)
#pragma unroll
    for (int u = 0; u < 2; ++u)
      pc[c][u] = cur[((size_t)c * Mc + b) * H1 + hb + tid + u * 256];

  for (int tl = 0; tl < tc; ++tl) {
#pragma unroll
    for (int u = 0; u < 2; ++u) {
      float zsum = 0.f;
#pragma unroll
      for (int c = 0; c < HC; ++c) {
        float v = vdl[c][u], i = idl[c][u];
        float vdec = v + 0.1f * (i - v);
        float idec = 0.8f * i;
        bool z = (vdec - 1.0f) > 0.f;
        vdl[c][u] = z ? 0.f : vdec;
        idl[c][u] = idec + pc[c][u];
        zsum += z ? 1.f : 0.f;
      }
      float v = vsl[u], i = isl[u];
      float vdec = v + 0.1f * (i - v);
      float idec = 0.8f * i;
      bool z = (vdec - 1.0f) > 0.f;
      vsl[u] = z ? 0.f : vdec;
      isl[u] = idec + zsum;
      zls[tid + u * 256] = z ? 1.f : 0.f;
    }
    if (tl + 1 < tc) {
#pragma unroll
      for (int c = 0; c < HC; ++c)
#pragma unroll
        for (int u = 0; u < 2; ++u)
          pc[c][u] = cur[((size_t)c * Mc + (tl + 1) * B + b) * H1 + hb + tid + u * 256];
    }
    __syncthreads();
    {
      const int g = tid >> 4, li = tid & 15;
      if (g < NOUT) {
        float s = 0.f;
#pragma unroll
        for (int j = 0; j < 32; ++j) {
          int i2 = li + 16 * j;
          s += zls[i2] * wols[i2 * NOUT + g];
        }
        s += __shfl_xor(s, 1); s += __shfl_xor(s, 2);
        s += __shfl_xor(s, 4); s += __shfl_xor(s, 8);
        if (li == 0) cols[g] = s;
      }
    }
    __syncthreads();
    if (tid < NOUT) {
      float vdec = vo + 0.1f * (io - vo);
      float idec = 0.8f * io;
      bool z = (vdec - 1.0f) > 0.f;
      vo = z ? 0.f : vdec;
      io = idec + cols[tid];
      sp_g[((size_t)(t0 + tl) * B + b) * (OC * NOUT) + oc * NOUT + tid] = z ? 1.f : 0.f;
    }
  }

#pragma unroll
  for (int c = 0; c < HC; ++c)
#pragma unroll
    for (int u = 0; u < 2; ++u) {
      size_t o = ((size_t)c * B + b) * H1 + hb + tid + u * 256;
      vdh[o] = vdl[c][u]; idh[o] = idl[c][u];
    }
#pragma unroll
  for (int u = 0; u < 2; ++u) {
    size_t o = (size_t)b * H1 + hb + tid + u * 256;
    vsh[o] = vsl[u]; ish[o] = isl[u];
  }
  if (tid < NOUT) {
    vdo[(oc * B + b) * NOUT + tid] = vo;
    ido[(oc * B + b) * NOUT + tid] = io;
  }
}

// final readout integration over stored output spikes
__global__ __launch_bounds__(256) void integrate_out(
    const float* __restrict__ sp_g, float* __restrict__ out) {
  int i = blockIdx.x * 256 + threadIdx.x;
  if (i >= B * NOUT) return;
  int b = i / NOUT, o = i % NOUT;
  float vr = 0.f, ir = 0.f;
  for (int t = 0; t < T; ++t) {
    const float* p = sp_g + ((size_t)(t * B + b) * OC) * NOUT + o;
    float ssum = ((p[0] + p[NOUT]) + p[2 * NOUT]) + p[3 * NOUT];
    float vn = vr + 0.1f * (ir - vr);
    ir = 0.8f * ir + ssum;
    vr = vn;
    out[(size_t)(t * B + b) * NOUT + o] = vn;
  }
}

extern "C" void kernel_launch(void* const* d_in, const int* in_sizes, int n_in,
                              void* d_out, int out_size, void* d_ws, size_t ws_size,
                              hipStream_t stream) {
  const float* x  = (const float*)d_in[0];
  const float* wh = (const float*)d_in[1];
  const float* wo = (const float*)d_in[2];
  float* out = (float*)d_out;
  char* ws = (char*)d_ws;

  unsigned short* wth = (unsigned short*)ws;
  unsigned short* wtl = wth + (size_t)HC * NK * H1;
  float* st  = (float*)(wtl + (size_t)HC * NK * H1);
  float* vdh = st;
  float* idh = vdh + HBH;
  float* vsh = idh + HBH;
  float* ish = vsh + (size_t)B * H1;
  float* vdo = ish + (size_t)B * H1;
  float* ido = vdo + OC * B * NOUT;
  float* sp_g = ido + OC * B * NOUT;
  float* dyn = sp_g + (size_t)T * B * OC * NOUT;
  const int NSTATE = (int)(sp_g - st);

  size_t fixed_bytes = (size_t)((char*)dyn - ws);
  size_t avail = (ws_size > fixed_bytes + 256) ? ws_size - fixed_bytes - 256 : 0;
  const size_t per_t = (size_t)HC * B * H1 * 4 + (size_t)B * FS2 * 2 * 2;  // 4MB
  int Tc = (int)(avail / per_t);
  if (Tc > T) Tc = T;
  if (Tc >= 2) Tc &= ~1;
  if (Tc < 1) Tc = 1;

  float* cur = dyn;
  unsigned short* xh = (unsigned short*)(cur + (size_t)Tc * HC * B * H1);
  unsigned short* xl = xh + (size_t)Tc * B * FS2;

  init_state<<<(NSTATE + 255) / 256, 256, 0, stream>>>(st, NSTATE);
  conv_w<<<dim3(H1 / 64, NK / 64, HC), 256, 0, stream>>>(wh, wth, wtl);

  for (int t0 = 0; t0 < T; t0 += Tc) {
    int tc = (T - t0 < Tc) ? (T - t0) : Tc;
    int Mc = tc * B;
    int n4 = Mc * (FS2 / 4);
    int cb = (n4 + 255) / 256; if (cb > 2048) cb = 2048;
    conv_x<<<cb, 256, 0, stream>>>((const float4*)(x + (size_t)t0 * B * FS2),
                                   (ushort4*)xh, (ushort4*)xl, n4);
    int nMblk = (Mc + 255) / 256;
    gemm_split<<<HC * 8 * nMblk, 512, 0, stream>>>(xh, xl, wth, wtl, cur, Mc, nMblk);
    seq_chunk<<<B * OC, 256, 0, stream>>>(cur, wo, vdh, idh, vsh, ish,
                                          vdo, ido, sp_g, t0, tc, Mc);
  }
  integrate_out<<<(B * NOUT + 255) / 256, 256, 0, stream>>>(sp_g, out);
}